// Round 11
// baseline (276.080 us; speedup 1.0000x reference)
//
#include <hip/hip_runtime.h>

// ---------------------------------------------------------------------------
// Channel attention (XCA): B=4, N=4096, C=768, H=8, HD=96, fp32 in/out.
// R13: gemm_bt = R7 skeleton (256x128 / BK=64 / 8 waves 4x2 of 64x64 /
// TRIPLE-buffered 3x48KB, 2-tile prefetch) collapsed to ONE barrier per
// K-tile with 32 MFMA/wave between barriers (R11's loop form):
//   per tile t: { if(t<10) ST(t+2 -> buf[(t+2)%3]);  RD 16 frags (buf t%3);
//                 32 MFMA;  VM(6) [t==10: VM(0)];  BAR }
// WAR: ST(t+2) overwrites buf[(t-1)%3], last read at t-1, separated by
// BAR(t-1). RAW: tile t's 6 loads issued at t-2 (~4800cy lead), forced by
// VM(6) at end of t-1. m233 rationale: barrier+stage overhead dominates
// phase loops; 8 bar/tile (R7, best measured) -> 1 bar/tile.
// ---------------------------------------------------------------------------

using bf16x8 = __attribute__((ext_vector_type(8))) short;
using f32x4  = __attribute__((ext_vector_type(4))) float;

#define SCALE_ 0.10206207261596575f   // 96^-0.5
#define KD 768

__device__ __forceinline__ unsigned short f2bf(float f) {
    unsigned int u = __builtin_bit_cast(unsigned int, f);
    u += 0x7FFFu + ((u >> 16) & 1u);          // RNE, finite inputs only
    return (unsigned short)(u >> 16);
}
__device__ __forceinline__ float bf2f(unsigned short h) {
    unsigned int u = ((unsigned int)h) << 16;
    return __builtin_bit_cast(float, u);
}

__device__ __forceinline__ void glds16(const unsigned short* g, unsigned short* l) {
    __builtin_amdgcn_global_load_lds(
        (const __attribute__((address_space(1))) void*)g,
        (__attribute__((address_space(3))) void*)l, 16, 0, 0);
}

// sum of squares of 8 bf16 packed in a frag
__device__ __forceinline__ float ssq8(bf16x8 v) {
    uint4 u = __builtin_bit_cast(uint4, v);
    unsigned a[4] = {u.x, u.y, u.z, u.w};
    float s = 0.f;
    #pragma unroll
    for (int i = 0; i < 4; i++) {
        float lo = __builtin_bit_cast(float, a[i] << 16);
        float hi = __builtin_bit_cast(float, a[i] & 0xFFFF0000u);
        s += lo * lo + hi * hi;
    }
    return s;
}

// ---------------------------------------------------------------------------
// fp32 -> bf16 bulk convert (memory-bound). 8 elems/thread.
// ---------------------------------------------------------------------------
__global__ void f32_to_bf16_k(const float* __restrict__ in,
                              unsigned short* __restrict__ out)
{
    size_t idx = ((size_t)blockIdx.x * 256 + threadIdx.x) * 8;
    float4 v0 = *(const float4*)&in[idx];
    float4 v1 = *(const float4*)&in[idx + 4];
    unsigned short h[8];
    h[0] = f2bf(v0.x); h[1] = f2bf(v0.y); h[2] = f2bf(v0.z); h[3] = f2bf(v0.w);
    h[4] = f2bf(v1.x); h[5] = f2bf(v1.y); h[6] = f2bf(v1.z); h[7] = f2bf(v1.w);
    *(bf16x8*)&out[idx] = *(bf16x8*)h;
}

// ---------------------------------------------------------------------------
// Weight transpose + fp32->bf16: W[K][N] -> Wt[N][K]. block(32,8).
// ---------------------------------------------------------------------------
__global__ void transpose_to_bf16(const float* __restrict__ W,
                                  unsigned short* __restrict__ Wt,
                                  int K, int N)
{
    __shared__ float tile[32][33];
    int n0 = blockIdx.x * 32, k0 = blockIdx.y * 32;
    int tx = threadIdx.x, ty = threadIdx.y;
    #pragma unroll
    for (int i = 0; i < 32; i += 8)
        tile[ty + i][tx] = W[(size_t)(k0 + ty + i) * N + n0 + tx];
    __syncthreads();
    #pragma unroll
    for (int i = 0; i < 32; i += 8)
        Wt[(size_t)(n0 + ty + i) * K + k0 + tx] = f2bf(tile[tx][ty + i]);
}

// ---------------------------------------------------------------------------
// GEMM: C = A[M][768] * Bt[N][768]^T, bf16. 256x128 block, BK=64, 8 waves
// 4x2 (wr=w>>1 owns 64 rows, wc=w&1 owns 64 cols), per-wave 4x4 frags of
// 16x16x32 MFMA x2 k-halves = 32 MFMA/tile. Fragment-order 1KB LDS blocks:
//   A: block = kc*16 + row16 (32 blocks, 32KB/tile)
//   B: block = kc*8  + row16 (16 blocks, 16KB/tile)
// Block holds rows row16*16+(lane&15), k = kc*32+(lane>>4)*8 at lane*16B ->
// glds16 staging and ds_read_b128 fragment reads both lane-sequential.
// Per wave per tile: ST = 6 glds16 (A h0,h1 + B), RD = 16 ds_read_b128.
// MODE 0: write transposed bf16 Qt[bh][d][n]     (out0)
// MODE 1: cols<768 -> Kt[bh][d][n] (out0); cols>=768 -> Vb[m][768] (out1)
// MODE 2: fp32 + bias row-major (out0)
// ---------------------------------------------------------------------------

#define BAR __builtin_amdgcn_s_barrier()
#define VM(n) asm volatile("s_waitcnt vmcnt(" #n ")" ::: "memory")

#define ST(tt, bi) do { \
    _Pragma("unroll") \
    for (int h_ = 0; h_ < 2; h_++) { \
        const int r16a_ = h_ * 8 + w; \
        _Pragma("unroll") \
        for (int c_ = 0; c_ < 2; c_++) \
            glds16(gA + (size_t)(r16a_ * 16) * KD + (tt) * 64 + c_ * 32, \
                   &As[bi][(c_ * 16 + r16a_) * 512]); \
    } \
    _Pragma("unroll") \
    for (int c_ = 0; c_ < 2; c_++) \
        glds16(gB + (size_t)(w * 16) * KD + (tt) * 64 + c_ * 32, \
               &Bs[bi][(c_ * 8 + w) * 512]); \
} while (0)

template<int MODE>
__global__ __launch_bounds__(512, 1) void gemm_bt(
    const unsigned short* __restrict__ A, const unsigned short* __restrict__ Bt,
    const float* __restrict__ bias, void* __restrict__ out0, void* __restrict__ out1,
    int M, int N)
{
    __shared__ unsigned short As[3][16384];   // 3 x 32KB (32 blocks of 1KB)
    __shared__ unsigned short Bs[3][8192];    // 3 x 16KB (16 blocks of 1KB)

    const int Nt = gridDim.x, Mt = gridDim.y;
    const int lin = blockIdx.y * Nt + blockIdx.x;
    const int xcd = lin & 7, li = lin >> 3;
    const int band = Mt >> 3;
    const int mt = xcd * band + (li % band);
    const int nt = li / band;
    const int bm = mt * 256, bn = nt * 128;

    const int t = threadIdx.x, lane = t & 63, w = t >> 6;
    const int wr = w >> 1, wc = w & 1;            // 4 x 2 wave grid
    const int mf = lane & 15, quad = lane >> 4;

    const unsigned short* gA = A  + (size_t)(bm + (lane & 15)) * KD + (lane >> 4) * 8;
    const unsigned short* gB = Bt + (size_t)(bn + (lane & 15)) * KD + (lane >> 4) * 8;

    f32x4 acc[4][4] = {};

    // prologue: tiles 0,1 -> bufs 0,1 (6 loads each); VM(6) forces tile 0.
    ST(0, 0); ST(1, 1);
    VM(6);
    BAR;

    int cur = 0;
    #pragma unroll 1
    for (int tt = 0; tt < 12; ++tt) {
        int nb = cur - 1; if (nb < 0) nb = 2;     // (tt+2)%3
        if (tt < 10) ST(tt + 2, nb);              // overwrite buf read at tt-1

        bf16x8 a[4][2], b[4][2];
        #pragma unroll
        for (int i = 0; i < 4; i++)
            #pragma unroll
            for (int kk = 0; kk < 2; kk++)
                a[i][kk] = *(const bf16x8*)&As[cur][(kk * 16 + wr * 4 + i) * 512 + lane * 8];
        #pragma unroll
        for (int j = 0; j < 4; j++)
            #pragma unroll
            for (int kk = 0; kk < 2; kk++)
                b[j][kk] = *(const bf16x8*)&Bs[cur][(kk * 8 + wc * 4 + j) * 512 + lane * 8];

        __builtin_amdgcn_s_setprio(1);
        #pragma unroll
        for (int i = 0; i < 4; i++)
            #pragma unroll
            for (int j = 0; j < 4; j++)
                #pragma unroll
                for (int kk = 0; kk < 2; kk++)
                    acc[i][j] = __builtin_amdgcn_mfma_f32_16x16x32_bf16(a[i][kk], b[j][kk], acc[i][j], 0, 0, 0);
        __builtin_amdgcn_s_setprio(0);

        if (tt < 10) { VM(6); }                   // tile tt+1 (issued tt-1) done
        else if (tt == 10) { VM(0); }             // tile 11 done
        BAR;
        cur = cur + 1; if (cur == 3) cur = 0;
    }

    // C/D layout: col = lane&15, row = quad*4 + r
    if constexpr (MODE == 2) {
        float* C = (float*)out0;
        #pragma unroll
        for (int i = 0; i < 4; i++) {
            int row0 = bm + wr * 64 + i * 16 + quad * 4;
            #pragma unroll
            for (int j = 0; j < 4; j++) {
                int col = bn + wc * 64 + j * 16 + mf;
                float bv = bias[col];
                #pragma unroll
                for (int r = 0; r < 4; r++)
                    C[(size_t)(row0 + r) * N + col] = acc[i][j][r] + bv;
            }
        }
    } else {
        unsigned short* Tr = (unsigned short*)out0;   // Qt or Kt [bh][96][4096]
        unsigned short* Vb = (unsigned short*)out1;   // [16384][768]
        const bool kpart = (MODE == 0) || (bn < 768); // uniform (bn mult of 128)
        #pragma unroll
        for (int i = 0; i < 4; i++) {
            int row0 = bm + wr * 64 + i * 16 + quad * 4;  // global token index
            int bb = row0 >> 12, n = row0 & 4095;
            #pragma unroll
            for (int j = 0; j < 4; j++) {
                int c = bn + wc * 64 + j * 16 + mf;
                if (kpart) {
                    int h = (c * 683) >> 16;          // floor(c/96) for c<768
                    int d = c - h * 96;
                    size_t o = ((size_t)((bb * 8 + h) * 96 + d)) * 4096 + n;
                    ushort4 v4;
                    v4.x = f2bf(acc[i][j][0]); v4.y = f2bf(acc[i][j][1]);
                    v4.z = f2bf(acc[i][j][2]); v4.w = f2bf(acc[i][j][3]);
                    *(ushort4*)&Tr[o] = v4;
                } else {
                    int cv = c - 768;
                    #pragma unroll
                    for (int r = 0; r < 4; r++)
                        Vb[(size_t)(row0 + r) * 768 + cv] = f2bf(acc[i][j][r]);
                }
            }
        }
    }
}

#undef ST
#undef VM
#undef BAR

// ---------------------------------------------------------------------------
// S-gram: Spart[bh][s][96][96] = sum over 512-n window of Qt[d][n]*Kt[e][n].
// ---------------------------------------------------------------------------
__global__ __launch_bounds__(256) void s_gemm(
    const unsigned short* __restrict__ Qt, const unsigned short* __restrict__ Kt,
    float* __restrict__ Spart, float* __restrict__ ssq)
{
    __shared__ unsigned short Qs[2][12 * 512];
    __shared__ unsigned short Ks[2][12 * 512];
    const int s = blockIdx.x, bh = blockIdx.y;
    const int t = threadIdx.x, lane = t & 63, w = t >> 6;
    const int m0 = (w >> 1) * 48, n0w = (w & 1) * 48;
    const int mf = lane & 15, quad = lane >> 4;
    const int srow = lane & 15, skc = (lane >> 4) * 8;
    const int nwin = s * 512;

    const unsigned short* Qg = Qt + (size_t)bh * 96 * 4096;
    const unsigned short* Kg = Kt + (size_t)bh * 96 * 4096;

    f32x4 acc[3][3] = {};
    float sq[3] = {0.f, 0.f, 0.f}, sk[3] = {0.f, 0.f, 0.f};

    #pragma unroll
    for (int c = 0; c < 3; c++) {
        int bi = w * 3 + c, kc = bi / 6, g = bi % 6;
        size_t go = (size_t)(g * 16 + srow) * 4096 + nwin + kc * 32 + skc;
        glds16(Qg + go, &Qs[0][bi * 512]);
        glds16(Kg + go, &Ks[0][bi * 512]);
    }

    for (int it = 0; it < 8; it++) {
        const int cur = it & 1;
        __syncthreads();
        if (it + 1 < 8) {
            const int nxt = cur ^ 1;
            const int nn = nwin + (it + 1) * 64;
            #pragma unroll
            for (int c = 0; c < 3; c++) {
                int bi = w * 3 + c, kc = bi / 6, g = bi % 6;
                size_t go = (size_t)(g * 16 + srow) * 4096 + nn + kc * 32 + skc;
                glds16(Qg + go, &Qs[nxt][bi * 512]);
                glds16(Kg + go, &Ks[nxt][bi * 512]);
            }
        }
        #pragma unroll
        for (int kk = 0; kk < 2; kk++) {
            bf16x8 a[3], b[3];
            #pragma unroll
            for (int i = 0; i < 3; i++)
                a[i] = *(const bf16x8*)&Qs[cur][(kk * 6 + (w >> 1) * 3 + i) * 512 + lane * 8];
            #pragma unroll
            for (int j = 0; j < 3; j++)
                b[j] = *(const bf16x8*)&Ks[cur][(kk * 6 + (w & 1) * 3 + j) * 512 + lane * 8];
            if ((w & 1) == 0) {
                #pragma unroll
                for (int i = 0; i < 3; i++) sq[i] += ssq8(a[i]);
            }
            if ((w >> 1) == 0) {
                #pragma unroll
                for (int j = 0; j < 3; j++) sk[j] += ssq8(b[j]);
            }
            #pragma unroll
            for (int i = 0; i < 3; i++)
                #pragma unroll
                for (int j = 0; j < 3; j++)
                    acc[i][j] = __builtin_amdgcn_mfma_f32_16x16x32_bf16(a[i], b[j], acc[i][j], 0, 0, 0);
        }
    }

    if ((w & 1) == 0) {
        #pragma unroll
        for (int i = 0; i < 3; i++) {
            float v = sq[i];
            v += __shfl_xor(v, 16, 64);
            v += __shfl_xor(v, 32, 64);
            if (lane < 16) atomicAdd(&ssq[bh * 96 + m0 + i * 16 + lane], v);
        }
    }
    if ((w >> 1) == 0) {
        #pragma unroll
        for (int j = 0; j < 3; j++) {
            float v = sk[j];
            v += __shfl_xor(v, 16, 64);
            v += __shfl_xor(v, 32, 64);
            if (lane < 16) atomicAdd(&ssq[3072 + bh * 96 + n0w + j * 16 + lane], v);
        }
    }

    float* outp = Spart + (size_t)(bh * 8 + s) * 9216;
    #pragma unroll
    for (int i = 0; i < 3; i++)
        #pragma unroll
        for (int j = 0; j < 3; j++) {
            int e  = n0w + j * 16 + mf;
            int d0 = m0 + i * 16 + quad * 4;
            #pragma unroll
            for (int r = 0; r < 4; r++)
                outp[(d0 + r) * 96 + e] = acc[i][j][r];
        }
}

// ---------------------------------------------------------------------------
// Softmax, wave-per-row: grid(24, 32bh) x 256 thr.
// ---------------------------------------------------------------------------
__global__ __launch_bounds__(256) void softmax_k(
    const float* __restrict__ Spart, const float* __restrict__ ssq,
    unsigned short* __restrict__ P)
{
    const int bh = blockIdx.y;
    const int d  = blockIdx.x * 4 + (threadIdx.x >> 6);
    const int lane = threadIdx.x & 63;

    const float sr = SCALE_ / fmaxf(sqrtf(ssq[bh * 96 + d]), 1e-12f);

    const float* Sp = Spart + (size_t)bh * 8 * 9216 + d * 96;
    float sa = 0.f, sb = 0.f;
    #pragma unroll
    for (int ch = 0; ch < 8; ch++) {
        sa += Sp[ch * 9216 + lane];
        if (lane < 32) sb += Sp[ch * 9216 + 64 + lane];
    }
    float ka = 1.0f / fmaxf(sqrtf(ssq[3072 + bh * 96 + lane]), 1e-12f);
    float va = sa * sr * ka;
    float vb = -1e30f;
    if (lane < 32) {
        float kb = 1.0f / fmaxf(sqrtf(ssq[3072 + bh * 96 + 64 + lane]), 1e-12f);
        vb = sb * sr * kb;
    }

    float m = fmaxf(va, vb);
    #pragma unroll
    for (int off = 32; off >= 1; off >>= 1)
        m = fmaxf(m, __shfl_xor(m, off, 64));

    float ea = __expf(va - m);
    float eb = (lane < 32) ? __expf(vb - m) : 0.f;
    float ssum = ea + eb;
    #pragma unroll
    for (int off = 32; off >= 1; off >>= 1)
        ssum += __shfl_xor(ssum, off, 64);

    float inv = 1.0f / ssum;
    unsigned short* Pr = P + (size_t)bh * 9216 + d * 96;
    Pr[lane] = f2bf(ea * inv);
    if (lane < 32) Pr[64 + lane] = f2bf(eb * inv);
}

// ---------------------------------------------------------------------------
// x[n][d] = sum_e V[n][e] * P[d][e] per (b,h). V from compact Vb[m][768].
// ---------------------------------------------------------------------------
__global__ __launch_bounds__(256) void pv_gemm(
    const unsigned short* __restrict__ Vb, const unsigned short* __restrict__ P,
    unsigned short* __restrict__ X)
{
    __shared__ unsigned short Ps[96][104];
    int ntile = blockIdx.x, bh = blockIdx.y;
    int b = bh >> 3, h = bh & 7;
    int t = threadIdx.x, lane = t & 63, w = t >> 6;

    const unsigned short* Pg = P + (size_t)bh * 9216;
    #pragma unroll
    for (int i = 0; i < 9; i++) {
        int idx4 = t + 256 * i;
        int row = idx4 / 24, c4 = (idx4 - row * 24) * 4;
        *(ushort4*)&Ps[row][c4] = *(const ushort4*)&Pg[row * 96 + c4];
    }
    __syncthreads();

    const unsigned short* Vbase = Vb + (size_t)b * 4096 * 768 + h * 96;
    int mf = lane & 15, k8 = (lane >> 4) * 8;
    f32x4 acc[2][6] = {};
    #pragma unroll
    for (int k = 0; k < 3; k++) {
        bf16x8 a[2], bb[6];
        #pragma unroll
        for (int i = 0; i < 2; i++) {
            int row = ntile * 128 + w * 32 + i * 16 + mf;
            a[i] = *(const bf16x8*)&Vbase[(size_t)row * 768 + k * 32 + k8];
        }
        #pragma unroll
        for (int j = 0; j < 6; j++)
            bb[j] = *(const bf16x8*)&Ps[j * 16 + mf][k * 32 + k8];
        #pragma unroll
        for (int i = 0; i < 2; i++)
            #pragma unroll
            for (int j = 0; j < 6; j++)
                acc[i][j] = __builtin_amdgcn_mfma_f32_16x16x32_bf16(a[i], bb[j], acc[i][j], 0, 0, 0);
    }
    #pragma unroll
    for (int i = 0; i < 2; i++)
        #pragma unroll
        for (int j = 0; j < 6; j++)
            #pragma unroll
            for (int r = 0; r < 4; r++) {
                int n_tok = ntile * 128 + w * 32 + i * 16 + (lane >> 4) * 4 + r;
                int c = h * 96 + j * 16 + mf;
                X[((size_t)b * 4096 + n_tok) * 768 + c] = f2bf(acc[i][j][r]);
            }
}

// ---------------------------------------------------------------------------
extern "C" void kernel_launch(void* const* d_in, const int* in_sizes, int n_in,
                              void* d_out, int out_size, void* d_ws, size_t ws_size,
                              hipStream_t stream)
{
    (void)in_sizes; (void)n_in; (void)out_size; (void)ws_size;
    const float* ctx   = (const float*)d_in[0];
    const float* dep   = (const float*)d_in[1];
    const float* Wq    = (const float*)d_in[2];
    const float* Wkv   = (const float*)d_in[3];
    const float* Wproj = (const float*)d_in[4];
    const float* bproj = (const float*)d_in[5];
    float* out = (float*)d_out;

    char* p = (char*)d_ws;
    auto carve = [&](size_t bytes) {
        char* r = p;
        p += (bytes + 255) & ~(size_t)255;
        return r;
    };
    unsigned short* WqT    = (unsigned short*)carve((size_t)768 * 768 * 2);
    unsigned short* WkvT   = (unsigned short*)carve((size_t)1536 * 768 * 2);
    unsigned short* WprojT = (unsigned short*)carve((size_t)768 * 768 * 2);
    unsigned short* Qt     = (unsigned short*)carve((size_t)32 * 96 * 4096 * 2);
    unsigned short* Kt     = (unsigned short*)carve((size_t)32 * 96 * 4096 * 2);
    unsigned short* Vb     = (unsigned short*)carve((size_t)16384 * 768 * 2);
    unsigned short* Xb     = (unsigned short*)carve((size_t)16384 * 768 * 2);
    float*          ssq    = (float*)carve((size_t)2 * 3072 * 4);
    float*          Spart  = (float*)carve((size_t)32 * 8 * 9216 * 4);
    unsigned short* Pb     = (unsigned short*)carve((size_t)32 * 9216 * 2);
    unsigned short* depB   = (unsigned short*)carve((size_t)16384 * 768 * 2);
    // ctx-bf16 aliases Xb: Q-gemm consumes it before pv_gemm writes Xb.
    unsigned short* ctxB   = Xb;

    hipMemsetAsync(ssq, 0, 2 * 3072 * 4, stream);

    f32_to_bf16_k<<<6144, 256, 0, stream>>>(ctx, ctxB);
    f32_to_bf16_k<<<6144, 256, 0, stream>>>(dep, depB);

    dim3 tb(32, 8);
    transpose_to_bf16<<<dim3(24, 24), tb, 0, stream>>>(Wq, WqT, 768, 768);
    transpose_to_bf16<<<dim3(48, 24), tb, 0, stream>>>(Wkv, WkvT, 768, 1536);
    transpose_to_bf16<<<dim3(24, 24), tb, 0, stream>>>(Wproj, WprojT, 768, 768);

    gemm_bt<0><<<dim3(6, 64), 512, 0, stream>>>(ctxB, WqT, nullptr, Qt, nullptr, 16384, 768);
    gemm_bt<1><<<dim3(12, 64), 512, 0, stream>>>(depB, WkvT, nullptr, Kt, Vb, 16384, 1536);

    s_gemm<<<dim3(8, 32), 256, 0, stream>>>(Qt, Kt, Spart, ssq);
    softmax_k<<<dim3(24, 32), 256, 0, stream>>>(Spart, ssq, Pb);
    pv_gemm<<<dim3(32, 32), 256, 0, stream>>>(Vb, Pb, Xb);
    gemm_bt<2><<<dim3(6, 64), 512, 0, stream>>>(Xb, WprojT, bproj, out, nullptr, 16384, 768);
}

// Round 12
// 222.731 us; speedup vs baseline: 1.2395x; 1.2395x over previous
//
#include <hip/hip_runtime.h>

// ---------------------------------------------------------------------------
// Channel attention (XCA): B=4, N=4096, C=768, H=8, HD=96, fp32 in/out.
// R14: revert to R7 (best measured: MODE1 69us, total 226.9) minus two
// measured negatives: (1) s_setprio removed from MFMA cluster (T5 is
// negative on barrier-lockstep GEMMs, m190); (2) the two f32->bf16
// converts merged into one launch. GEMM = 256x128 / BK=64 / 8 waves (4x2)
// / TRIPLE-buffered LDS (3x48KB), 4 phases per K-tile, 2-tile prefetch:
//  phi1: rdA(h0) rdB(n0) | stA(t+2,h0) | BAR MM(0,0) BAR
//  phi2:         rdB(n1) | stA(t+2,h1) | BAR MM(0,1) BAR
//  phi3: rdA(h1)         | stB(t+2)    | BAR MM(1,0) BAR
//  phi4:                 MM(1,1); VM(6) [t==10: VM(0)]; BAR
// Structural-plateau note: R9-R13 isolated depth/packing/occupancy/L2-order/
// barrier-count; all null or negative vs this config at K=768.
// ---------------------------------------------------------------------------

using bf16x8 = __attribute__((ext_vector_type(8))) short;
using f32x4  = __attribute__((ext_vector_type(4))) float;

#define SCALE_ 0.10206207261596575f   // 96^-0.5
#define KD 768

__device__ __forceinline__ unsigned short f2bf(float f) {
    unsigned int u = __builtin_bit_cast(unsigned int, f);
    u += 0x7FFFu + ((u >> 16) & 1u);          // RNE, finite inputs only
    return (unsigned short)(u >> 16);
}
__device__ __forceinline__ float bf2f(unsigned short h) {
    unsigned int u = ((unsigned int)h) << 16;
    return __builtin_bit_cast(float, u);
}

__device__ __forceinline__ void glds16(const unsigned short* g, unsigned short* l) {
    __builtin_amdgcn_global_load_lds(
        (const __attribute__((address_space(1))) void*)g,
        (__attribute__((address_space(3))) void*)l, 16, 0, 0);
}

// sum of squares of 8 bf16 packed in a frag
__device__ __forceinline__ float ssq8(bf16x8 v) {
    uint4 u = __builtin_bit_cast(uint4, v);
    unsigned a[4] = {u.x, u.y, u.z, u.w};
    float s = 0.f;
    #pragma unroll
    for (int i = 0; i < 4; i++) {
        float lo = __builtin_bit_cast(float, a[i] << 16);
        float hi = __builtin_bit_cast(float, a[i] & 0xFFFF0000u);
        s += lo * lo + hi * hi;
    }
    return s;
}

// ---------------------------------------------------------------------------
// fp32 -> bf16 bulk convert, both tensors in one launch (12288 blocks).
// ---------------------------------------------------------------------------
__global__ void f32_to_bf16_k2(const float* __restrict__ in0,
                               unsigned short* __restrict__ out0,
                               const float* __restrict__ in1,
                               unsigned short* __restrict__ out1)
{
    int bid = blockIdx.x;
    const float* in;
    unsigned short* out;
    if (bid < 6144) { in = in0; out = out0; }
    else            { in = in1; out = out1; bid -= 6144; }
    size_t idx = ((size_t)bid * 256 + threadIdx.x) * 8;
    float4 v0 = *(const float4*)&in[idx];
    float4 v1 = *(const float4*)&in[idx + 4];
    unsigned short h[8];
    h[0] = f2bf(v0.x); h[1] = f2bf(v0.y); h[2] = f2bf(v0.z); h[3] = f2bf(v0.w);
    h[4] = f2bf(v1.x); h[5] = f2bf(v1.y); h[6] = f2bf(v1.z); h[7] = f2bf(v1.w);
    *(bf16x8*)&out[idx] = *(bf16x8*)h;
}

// ---------------------------------------------------------------------------
// Weight transpose + fp32->bf16: W[K][N] -> Wt[N][K]. block(32,8).
// ---------------------------------------------------------------------------
__global__ void transpose_to_bf16(const float* __restrict__ W,
                                  unsigned short* __restrict__ Wt,
                                  int K, int N)
{
    __shared__ float tile[32][33];
    int n0 = blockIdx.x * 32, k0 = blockIdx.y * 32;
    int tx = threadIdx.x, ty = threadIdx.y;
    #pragma unroll
    for (int i = 0; i < 32; i += 8)
        tile[ty + i][tx] = W[(size_t)(k0 + ty + i) * N + n0 + tx];
    __syncthreads();
    #pragma unroll
    for (int i = 0; i < 32; i += 8)
        Wt[(size_t)(n0 + ty + i) * K + k0 + tx] = f2bf(tile[tx][ty + i]);
}

// ---------------------------------------------------------------------------
// GEMM: C = A[M][768] * Bt[N][768]^T, bf16. 256x128 block, BK=64, 8 waves
// in a 4x2 grid, each wave owns 64x64 (4x4 16x16x32 MFMA).
// LDS: 3 buffers x (A 32KB + B 16KB). Fragment-order 1KB LDS blocks:
// A block = kc*16+row16 (rows row16*16+(lane&15), k=kc*32+(lane>>4)*8),
// B block = kc*8+row16. glds16 staging and ds_read_b128 fragment reads
// are both lane-sequential (0 bank conflicts).
// MODE 0: write transposed bf16 Qt[bh][d][n]     (out0)
// MODE 1: cols<768 -> Kt[bh][d][n] (out0); cols>=768 -> Vb[m][768] (out1)
// MODE 2: fp32 + bias row-major (out0)
// ---------------------------------------------------------------------------

#define BAR __builtin_amdgcn_s_barrier()
#define VM(n) asm volatile("s_waitcnt vmcnt(" #n ")" ::: "memory")

#define ST_A(sbase, tt, h) do { \
    _Pragma("unroll") \
    for (int c_ = 0; c_ < 2; c_++) \
        glds16(gA + (size_t)(((h) * 8 + w) * 16) * KD + (tt) * 64 + c_ * 32, \
               (sbase) + (c_ * 16 + (h) * 8 + w) * 512); \
} while (0)

#define ST_B(sbase, tt) do { \
    _Pragma("unroll") \
    for (int c_ = 0; c_ < 2; c_++) \
        glds16(gB + (size_t)(w * 16) * KD + (tt) * 64 + c_ * 32, \
               (sbase) + (c_ * 8 + w) * 512); \
} while (0)

#define RD_A(cbase, mh) do { \
    _Pragma("unroll") \
    for (int i_ = 0; i_ < 2; i_++) \
    _Pragma("unroll") \
    for (int kk_ = 0; kk_ < 2; kk_++) \
        a[i_][kk_] = *(const bf16x8*)&(cbase)[(kk_ * 16 + wr * 4 + (mh) * 2 + i_) * 512 + lane * 8]; \
} while (0)

#define RD_B(cbase, nh) do { \
    _Pragma("unroll") \
    for (int j_ = 0; j_ < 2; j_++) \
    _Pragma("unroll") \
    for (int kk_ = 0; kk_ < 2; kk_++) \
        b[nh][j_][kk_] = *(const bf16x8*)&(cbase)[(kk_ * 8 + wc * 4 + (nh) * 2 + j_) * 512 + lane * 8]; \
} while (0)

#define MM(mh, nh) do { \
    _Pragma("unroll") \
    for (int i_ = 0; i_ < 2; i_++) \
    _Pragma("unroll") \
    for (int j_ = 0; j_ < 2; j_++) \
    _Pragma("unroll") \
    for (int kk_ = 0; kk_ < 2; kk_++) \
        acc[(mh) * 2 + i_][(nh) * 2 + j_] = __builtin_amdgcn_mfma_f32_16x16x32_bf16( \
            a[i_][kk_], b[nh][j_][kk_], acc[(mh) * 2 + i_][(nh) * 2 + j_], 0, 0, 0); \
} while (0)

template<int MODE>
__global__ __launch_bounds__(512, 2) void gemm_bt(
    const unsigned short* __restrict__ A, const unsigned short* __restrict__ Bt,
    const float* __restrict__ bias, void* __restrict__ out0, void* __restrict__ out1,
    int M, int N)
{
    __shared__ unsigned short S[3 * 24576];      // 3 x (A 32KB + B 16KB)

    const int Nt = gridDim.x, Mt = gridDim.y;
    const int lin = blockIdx.y * Nt + blockIdx.x;
    const int xcd = lin & 7, li = lin >> 3;
    const int band = Mt >> 3;
    const int mt = xcd * band + (li % band);
    const int nt = li / band;
    const int bm = mt * 256, bn = nt * 128;

    const int t = threadIdx.x, lane = t & 63, w = t >> 6;
    const int wr = w >> 1, wc = w & 1;            // 4 x 2 wave grid
    const int mf = lane & 15, quad = lane >> 4;

    const unsigned short* gA = A  + (size_t)(bm + (lane & 15)) * KD + (lane >> 4) * 8;
    const unsigned short* gB = Bt + (size_t)(bn + (lane & 15)) * KD + (lane >> 4) * 8;

    f32x4 acc[4][4] = {};
    bf16x8 a[2][2], b[2][2][2];

    // prologue: stage tiles 0 and 1 completely (6 loads each)
    {
        unsigned short* a0 = S;                  unsigned short* b0 = S + 16384;
        unsigned short* a1 = S + 24576;          unsigned short* b1 = S + 24576 + 16384;
        ST_A(a0, 0, 0); ST_A(a0, 0, 1); ST_B(b0, 0);
        ST_A(a1, 1, 0); ST_A(a1, 1, 1); ST_B(b1, 1);
    }
    VM(6);   // tile0's 6 loads complete; tile1's 6 may remain in flight
    BAR;

    unsigned cur = 0;
    for (int tt = 0; tt < 12; ++tt) {
        unsigned short* cA = S + cur * 24576;
        unsigned short* cB = cA + 16384;
        unsigned sg = cur + 2; if (sg >= 3) sg -= 3;
        unsigned short* sA = S + sg * 24576;
        unsigned short* sB = sA + 16384;
        const bool st = (tt <= 9);

        // phi1
        RD_A(cA, 0); RD_B(cB, 0); if (st) ST_A(sA, tt + 2, 0);
        BAR; MM(0, 0); BAR;
        // phi2
        RD_B(cB, 1); if (st) ST_A(sA, tt + 2, 1);
        BAR; MM(0, 1); BAR;
        // phi3
        RD_A(cA, 1); if (st) ST_B(sB, tt + 2);
        BAR; MM(1, 0); BAR;
        // phi4
        MM(1, 1);
        if (tt < 10) { VM(6); }                   // chunks(tt+1) done
        else if (tt == 10) { VM(0); }             // chunks(11) done
        BAR;
        cur = cur + 1; if (cur == 3) cur = 0;
    }

    // C/D layout: col = lane&15, row = quad*4 + r
    if constexpr (MODE == 2) {
        float* C = (float*)out0;
        #pragma unroll
        for (int i = 0; i < 4; i++) {
            int row0 = bm + wr * 64 + i * 16 + quad * 4;
            #pragma unroll
            for (int j = 0; j < 4; j++) {
                int col = bn + wc * 64 + j * 16 + mf;
                float bv = bias[col];
                #pragma unroll
                for (int r = 0; r < 4; r++)
                    C[(size_t)(row0 + r) * N + col] = acc[i][j][r] + bv;
            }
        }
    } else {
        unsigned short* Tr = (unsigned short*)out0;   // Qt or Kt [bh][96][4096]
        unsigned short* Vb = (unsigned short*)out1;   // [16384][768]
        const bool kpart = (MODE == 0) || (bn < 768); // uniform (bn mult of 128)
        #pragma unroll
        for (int i = 0; i < 4; i++) {
            int row0 = bm + wr * 64 + i * 16 + quad * 4;  // global token index
            int bb = row0 >> 12, n = row0 & 4095;
            #pragma unroll
            for (int j = 0; j < 4; j++) {
                int c = bn + wc * 64 + j * 16 + mf;
                if (kpart) {
                    int h = (c * 683) >> 16;          // floor(c/96) for c<768
                    int d = c - h * 96;
                    size_t o = ((size_t)((bb * 8 + h) * 96 + d)) * 4096 + n;
                    ushort4 v4;
                    v4.x = f2bf(acc[i][j][0]); v4.y = f2bf(acc[i][j][1]);
                    v4.z = f2bf(acc[i][j][2]); v4.w = f2bf(acc[i][j][3]);
                    *(ushort4*)&Tr[o] = v4;
                } else {
                    int cv = c - 768;
                    #pragma unroll
                    for (int r = 0; r < 4; r++)
                        Vb[(size_t)(row0 + r) * 768 + cv] = f2bf(acc[i][j][r]);
                }
            }
        }
    }
}

#undef MM
#undef RD_A
#undef RD_B
#undef ST_A
#undef ST_B
#undef VM
#undef BAR

// ---------------------------------------------------------------------------
// S-gram: Spart[bh][s][96][96] = sum over 512-n window of Qt[d][n]*Kt[e][n].
// ---------------------------------------------------------------------------
__global__ __launch_bounds__(256) void s_gemm(
    const unsigned short* __restrict__ Qt, const unsigned short* __restrict__ Kt,
    float* __restrict__ Spart, float* __restrict__ ssq)
{
    __shared__ unsigned short Qs[2][12 * 512];
    __shared__ unsigned short Ks[2][12 * 512];
    const int s = blockIdx.x, bh = blockIdx.y;
    const int t = threadIdx.x, lane = t & 63, w = t >> 6;
    const int m0 = (w >> 1) * 48, n0w = (w & 1) * 48;
    const int mf = lane & 15, quad = lane >> 4;
    const int srow = lane & 15, skc = (lane >> 4) * 8;
    const int nwin = s * 512;

    const unsigned short* Qg = Qt + (size_t)bh * 96 * 4096;
    const unsigned short* Kg = Kt + (size_t)bh * 96 * 4096;

    f32x4 acc[3][3] = {};
    float sq[3] = {0.f, 0.f, 0.f}, sk[3] = {0.f, 0.f, 0.f};

    #pragma unroll
    for (int c = 0; c < 3; c++) {
        int bi = w * 3 + c, kc = bi / 6, g = bi % 6;
        size_t go = (size_t)(g * 16 + srow) * 4096 + nwin + kc * 32 + skc;
        glds16(Qg + go, &Qs[0][bi * 512]);
        glds16(Kg + go, &Ks[0][bi * 512]);
    }

    for (int it = 0; it < 8; it++) {
        const int cur = it & 1;
        __syncthreads();
        if (it + 1 < 8) {
            const int nxt = cur ^ 1;
            const int nn = nwin + (it + 1) * 64;
            #pragma unroll
            for (int c = 0; c < 3; c++) {
                int bi = w * 3 + c, kc = bi / 6, g = bi % 6;
                size_t go = (size_t)(g * 16 + srow) * 4096 + nn + kc * 32 + skc;
                glds16(Qg + go, &Qs[nxt][bi * 512]);
                glds16(Kg + go, &Ks[nxt][bi * 512]);
            }
        }
        #pragma unroll
        for (int kk = 0; kk < 2; kk++) {
            bf16x8 a[3], b[3];
            #pragma unroll
            for (int i = 0; i < 3; i++)
                a[i] = *(const bf16x8*)&Qs[cur][(kk * 6 + (w >> 1) * 3 + i) * 512 + lane * 8];
            #pragma unroll
            for (int j = 0; j < 3; j++)
                b[j] = *(const bf16x8*)&Ks[cur][(kk * 6 + (w & 1) * 3 + j) * 512 + lane * 8];
            if ((w & 1) == 0) {
                #pragma unroll
                for (int i = 0; i < 3; i++) sq[i] += ssq8(a[i]);
            }
            if ((w >> 1) == 0) {
                #pragma unroll
                for (int j = 0; j < 3; j++) sk[j] += ssq8(b[j]);
            }
            #pragma unroll
            for (int i = 0; i < 3; i++)
                #pragma unroll
                for (int j = 0; j < 3; j++)
                    acc[i][j] = __builtin_amdgcn_mfma_f32_16x16x32_bf16(a[i], b[j], acc[i][j], 0, 0, 0);
        }
    }

    if ((w & 1) == 0) {
        #pragma unroll
        for (int i = 0; i < 3; i++) {
            float v = sq[i];
            v += __shfl_xor(v, 16, 64);
            v += __shfl_xor(v, 32, 64);
            if (lane < 16) atomicAdd(&ssq[bh * 96 + m0 + i * 16 + lane], v);
        }
    }
    if ((w >> 1) == 0) {
        #pragma unroll
        for (int j = 0; j < 3; j++) {
            float v = sk[j];
            v += __shfl_xor(v, 16, 64);
            v += __shfl_xor(v, 32, 64);
            if (lane < 16) atomicAdd(&ssq[3072 + bh * 96 + n0w + j * 16 + lane], v);
        }
    }

    float* outp = Spart + (size_t)(bh * 8 + s) * 9216;
    #pragma unroll
    for (int i = 0; i < 3; i++)
        #pragma unroll
        for (int j = 0; j < 3; j++) {
            int e  = n0w + j * 16 + mf;
            int d0 = m0 + i * 16 + quad * 4;
            #pragma unroll
            for (int r = 0; r < 4; r++)
                outp[(d0 + r) * 96 + e] = acc[i][j][r];
        }
}

// ---------------------------------------------------------------------------
// Softmax, wave-per-row: grid(24, 32bh) x 256 thr.
// ---------------------------------------------------------------------------
__global__ __launch_bounds__(256) void softmax_k(
    const float* __restrict__ Spart, const float* __restrict__ ssq,
    unsigned short* __restrict__ P)
{
    const int bh = blockIdx.y;
    const int d  = blockIdx.x * 4 + (threadIdx.x >> 6);
    const int lane = threadIdx.x & 63;

    const float sr = SCALE_ / fmaxf(sqrtf(ssq[bh * 96 + d]), 1e-12f);

    const float* Sp = Spart + (size_t)bh * 8 * 9216 + d * 96;
    float sa = 0.f, sb = 0.f;
    #pragma unroll
    for (int ch = 0; ch < 8; ch++) {
        sa += Sp[ch * 9216 + lane];
        if (lane < 32) sb += Sp[ch * 9216 + 64 + lane];
    }
    float ka = 1.0f / fmaxf(sqrtf(ssq[3072 + bh * 96 + lane]), 1e-12f);
    float va = sa * sr * ka;
    float vb = -1e30f;
    if (lane < 32) {
        float kb = 1.0f / fmaxf(sqrtf(ssq[3072 + bh * 96 + 64 + lane]), 1e-12f);
        vb = sb * sr * kb;
    }

    float m = fmaxf(va, vb);
    #pragma unroll
    for (int off = 32; off >= 1; off >>= 1)
        m = fmaxf(m, __shfl_xor(m, off, 64));

    float ea = __expf(va - m);
    float eb = (lane < 32) ? __expf(vb - m) : 0.f;
    float ssum = ea + eb;
    #pragma unroll
    for (int off = 32; off >= 1; off >>= 1)
        ssum += __shfl_xor(ssum, off, 64);

    float inv = 1.0f / ssum;
    unsigned short* Pr = P + (size_t)bh * 9216 + d * 96;
    Pr[lane] = f2bf(ea * inv);
    if (lane < 32) Pr[64 + lane] = f2bf(eb * inv);
}

// ---------------------------------------------------------------------------
// x[n][d] = sum_e V[n][e] * P[d][e] per (b,h). V from compact Vb[m][768].
// ---------------------------------------------------------------------------
__global__ __launch_bounds__(256) void pv_gemm(
    const unsigned short* __restrict__ Vb, const unsigned short* __restrict__ P,
    unsigned short* __restrict__ X)
{
    __shared__ unsigned short Ps[96][104];
    int ntile = blockIdx.x, bh = blockIdx.y;
    int b = bh >> 3, h = bh & 7;
    int t = threadIdx.x, lane = t & 63, w = t >> 6;

    const unsigned short* Pg = P + (size_t)bh * 9216;
    #pragma unroll
    for (int i = 0; i < 9; i++) {
        int idx4 = t + 256 * i;
        int row = idx4 / 24, c4 = (idx4 - row * 24) * 4;
        *(ushort4*)&Ps[row][c4] = *(const ushort4*)&Pg[row * 96 + c4];
    }
    __syncthreads();

    const unsigned short* Vbase = Vb + (size_t)b * 4096 * 768 + h * 96;
    int mf = lane & 15, k8 = (lane >> 4) * 8;
    f32x4 acc[2][6] = {};
    #pragma unroll
    for (int k = 0; k < 3; k++) {
        bf16x8 a[2], bb[6];
        #pragma unroll
        for (int i = 0; i < 2; i++) {
            int row = ntile * 128 + w * 32 + i * 16 + mf;
            a[i] = *(const bf16x8*)&Vbase[(size_t)row * 768 + k * 32 + k8];
        }
        #pragma unroll
        for (int j = 0; j < 6; j++)
            bb[j] = *(const bf16x8*)&Ps[j * 16 + mf][k * 32 + k8];
        #pragma unroll
        for (int i = 0; i < 2; i++)
            #pragma unroll
            for (int j = 0; j < 6; j++)
                acc[i][j] = __builtin_amdgcn_mfma_f32_16x16x32_bf16(a[i], bb[j], acc[i][j], 0, 0, 0);
    }
    #pragma unroll
    for (int i = 0; i < 2; i++)
        #pragma unroll
        for (int j = 0; j < 6; j++)
            #pragma unroll
            for (int r = 0; r < 4; r++) {
                int n_tok = ntile * 128 + w * 32 + i * 16 + (lane >> 4) * 4 + r;
                int c = h * 96 + j * 16 + mf;
                X[((size_t)b * 4096 + n_tok) * 768 + c] = f2bf(acc[i][j][r]);
            }
}

// ---------------------------------------------------------------------------
extern "C" void kernel_launch(void* const* d_in, const int* in_sizes, int n_in,
                              void* d_out, int out_size, void* d_ws, size_t ws_size,
                              hipStream_t stream)
{
    (void)in_sizes; (void)n_in; (void)out_size; (void)ws_size;
    const float* ctx   = (const float*)d_in[0];
    const float* dep   = (const float*)d_in[1];
    const float* Wq    = (const float*)d_in[2];
    const float* Wkv   = (const float*)d_in[3];
    const float* Wproj = (const float*)d_in[4];
    const float* bproj = (const float*)d_in[5];
    float* out = (float*)d_out;

    char* p = (char*)d_ws;
    auto carve = [&](size_t bytes) {
        char* r = p;
        p += (bytes + 255) & ~(size_t)255;
        return r;
    };
    unsigned short* WqT    = (unsigned short*)carve((size_t)768 * 768 * 2);
    unsigned short* WkvT   = (unsigned short*)carve((size_t)1536 * 768 * 2);
    unsigned short* WprojT = (unsigned short*)carve((size_t)768 * 768 * 2);
    unsigned short* Qt     = (unsigned short*)carve((size_t)32 * 96 * 4096 * 2);
    unsigned short* Kt     = (unsigned short*)carve((size_t)32 * 96 * 4096 * 2);
    unsigned short* Vb     = (unsigned short*)carve((size_t)16384 * 768 * 2);
    unsigned short* Xb     = (unsigned short*)carve((size_t)16384 * 768 * 2);
    float*          ssq    = (float*)carve((size_t)2 * 3072 * 4);
    float*          Spart  = (float*)carve((size_t)32 * 8 * 9216 * 4);
    unsigned short* Pb     = (unsigned short*)carve((size_t)32 * 9216 * 2);
    unsigned short* depB   = (unsigned short*)carve((size_t)16384 * 768 * 2);
    // ctx-bf16 aliases Xb: Q-gemm consumes it before pv_gemm writes Xb.
    unsigned short* ctxB   = Xb;

    hipMemsetAsync(ssq, 0, 2 * 3072 * 4, stream);

    f32_to_bf16_k2<<<12288, 256, 0, stream>>>(ctx, ctxB, dep, depB);

    dim3 tb(32, 8);
    transpose_to_bf16<<<dim3(24, 24), tb, 0, stream>>>(Wq, WqT, 768, 768);
    transpose_to_bf16<<<dim3(48, 24), tb, 0, stream>>>(Wkv, WkvT, 768, 1536);
    transpose_to_bf16<<<dim3(24, 24), tb, 0, stream>>>(Wproj, WprojT, 768, 768);

    gemm_bt<0><<<dim3(6, 64), 512, 0, stream>>>(ctxB, WqT, nullptr, Qt, nullptr, 16384, 768);
    gemm_bt<1><<<dim3(12, 64), 512, 0, stream>>>(depB, WkvT, nullptr, Kt, Vb, 16384, 1536);

    s_gemm<<<dim3(8, 32), 256, 0, stream>>>(Qt, Kt, Spart, ssq);
    softmax_k<<<dim3(24, 32), 256, 0, stream>>>(Spart, ssq, Pb);
    pv_gemm<<<dim3(32, 32), 256, 0, stream>>>(Vb, Pb, Xb);
    gemm_bt<2><<<dim3(6, 64), 512, 0, stream>>>(Xb, WprojT, bproj, out, nullptr, 16384, 768);
}

// Round 13
// 214.157 us; speedup vs baseline: 1.2891x; 1.0400x over previous
//
#include <hip/hip_runtime.h>

// ---------------------------------------------------------------------------
// Channel attention (XCA): B=4, N=4096, C=768, H=8, HD=96, fp32 in/out.
// R15: R14 internals (best measured, 222.7us) + LAUNCH FUSION:
//  (a) Q-GEMM and KV-GEMM fused into one 1152-block dispatch -> Q's 0.5-round
//      tail (128 idle CUs @ 1 block/CU) backfills with KV blocks;
//  (b) converts + 3 weight transposes fused into one prep dispatch.
// 10 -> 7 dispatches. GEMM body unchanged: 256x128 / BK=64 / 8 waves (4x2)
// / triple-buffered 3x48KB / 4 phases per K-tile / 2-tile prefetch / no
// setprio (T5 negative on lockstep GEMMs, m190):
//  phi1: rdA(h0) rdB(n0) | stA(t+2,h0) | BAR MM(0,0) BAR
//  phi2:         rdB(n1) | stA(t+2,h1) | BAR MM(0,1) BAR
//  phi3: rdA(h1)         | stB(t+2)    | BAR MM(1,0) BAR
//  phi4:                 MM(1,1); VM(6) [t==10: VM(0)]; BAR
// Plateau note: R9-R13 isolated depth/packing/occupancy/L2-order/barrier-
// count; all null or negative vs this config at K=768.
// ---------------------------------------------------------------------------

using bf16x8 = __attribute__((ext_vector_type(8))) short;
using f32x4  = __attribute__((ext_vector_type(4))) float;

#define SCALE_ 0.10206207261596575f   // 96^-0.5
#define KD 768

__device__ __forceinline__ unsigned short f2bf(float f) {
    unsigned int u = __builtin_bit_cast(unsigned int, f);
    u += 0x7FFFu + ((u >> 16) & 1u);          // RNE, finite inputs only
    return (unsigned short)(u >> 16);
}
__device__ __forceinline__ float bf2f(unsigned short h) {
    unsigned int u = ((unsigned int)h) << 16;
    return __builtin_bit_cast(float, u);
}

__device__ __forceinline__ void glds16(const unsigned short* g, unsigned short* l) {
    __builtin_amdgcn_global_load_lds(
        (const __attribute__((address_space(1))) void*)g,
        (__attribute__((address_space(3))) void*)l, 16, 0, 0);
}

// sum of squares of 8 bf16 packed in a frag
__device__ __forceinline__ float ssq8(bf16x8 v) {
    uint4 u = __builtin_bit_cast(uint4, v);
    unsigned a[4] = {u.x, u.y, u.z, u.w};
    float s = 0.f;
    #pragma unroll
    for (int i = 0; i < 4; i++) {
        float lo = __builtin_bit_cast(float, a[i] << 16);
        float hi = __builtin_bit_cast(float, a[i] & 0xFFFF0000u);
        s += lo * lo + hi * hi;
    }
    return s;
}

// ---------------------------------------------------------------------------
// prep: fp32->bf16 converts (ctx, dep) + 3 weight transposes, one launch.
// blocks 0..12287: converts (8 elems/thread). 12288..14591: transposes.
// ---------------------------------------------------------------------------
__global__ void prep_k(const float* __restrict__ ctx, unsigned short* __restrict__ ctxB,
                       const float* __restrict__ dep, unsigned short* __restrict__ depB,
                       const float* __restrict__ Wq, unsigned short* __restrict__ WqT,
                       const float* __restrict__ Wkv, unsigned short* __restrict__ WkvT,
                       const float* __restrict__ Wproj, unsigned short* __restrict__ WprojT)
{
    __shared__ float tile[32][33];
    int bid = blockIdx.x;
    if (bid < 12288) {                            // converts
        const float* in; unsigned short* out;
        if (bid < 6144) { in = ctx; out = ctxB; }
        else            { in = dep; out = depB; bid -= 6144; }
        size_t idx = ((size_t)bid * 256 + threadIdx.x) * 8;
        float4 v0 = *(const float4*)&in[idx];
        float4 v1 = *(const float4*)&in[idx + 4];
        unsigned short h[8];
        h[0] = f2bf(v0.x); h[1] = f2bf(v0.y); h[2] = f2bf(v0.z); h[3] = f2bf(v0.w);
        h[4] = f2bf(v1.x); h[5] = f2bf(v1.y); h[6] = f2bf(v1.z); h[7] = f2bf(v1.w);
        *(bf16x8*)&out[idx] = *(bf16x8*)h;
        return;
    }
    bid -= 12288;                                 // transposes: W[K=768][N]->Wt[N][768]
    const float* W; unsigned short* Wt; int N, bx, by;
    if (bid < 576)       { W = Wq;    Wt = WqT;    N = 768;  bx = bid % 24;  by = bid / 24; }
    else if (bid < 1728) { bid -= 576;  W = Wkv;   Wt = WkvT; N = 1536; bx = bid % 48;  by = bid / 48; }
    else                 { bid -= 1728; W = Wproj; Wt = WprojT; N = 768; bx = bid % 24;  by = bid / 24; }
    int n0 = bx * 32, k0 = by * 32;
    int tx = threadIdx.x & 31, ty = threadIdx.x >> 5;
    #pragma unroll
    for (int i = 0; i < 32; i += 8)
        tile[ty + i][tx] = W[(size_t)(k0 + ty + i) * N + n0 + tx];
    __syncthreads();
    #pragma unroll
    for (int i = 0; i < 32; i += 8)
        Wt[(size_t)(n0 + ty + i) * 768 + k0 + tx] = f2bf(tile[tx][ty + i]);
}

// ---------------------------------------------------------------------------
// GEMM body macros (R14, measured best): 256x128 block, BK=64, 8 waves 4x2,
// per-wave 64x64 (4x4 16x16x32 MFMA). LDS: 3 buffers x (A 32KB + B 16KB),
// fragment-order 1KB blocks; glds16 staging and ds_read_b128 fragment reads
// both lane-sequential (0 bank conflicts).
// ---------------------------------------------------------------------------

#define BAR __builtin_amdgcn_s_barrier()
#define VM(n) asm volatile("s_waitcnt vmcnt(" #n ")" ::: "memory")

#define ST_A(sbase, tt, h) do { \
    _Pragma("unroll") \
    for (int c_ = 0; c_ < 2; c_++) \
        glds16(gA + (size_t)(((h) * 8 + w) * 16) * KD + (tt) * 64 + c_ * 32, \
               (sbase) + (c_ * 16 + (h) * 8 + w) * 512); \
} while (0)

#define ST_B(sbase, tt) do { \
    _Pragma("unroll") \
    for (int c_ = 0; c_ < 2; c_++) \
        glds16(gB + (size_t)(w * 16) * KD + (tt) * 64 + c_ * 32, \
               (sbase) + (c_ * 8 + w) * 512); \
} while (0)

#define RD_A(cbase, mh) do { \
    _Pragma("unroll") \
    for (int i_ = 0; i_ < 2; i_++) \
    _Pragma("unroll") \
    for (int kk_ = 0; kk_ < 2; kk_++) \
        a[i_][kk_] = *(const bf16x8*)&(cbase)[(kk_ * 16 + wr * 4 + (mh) * 2 + i_) * 512 + lane * 8]; \
} while (0)

#define RD_B(cbase, nh) do { \
    _Pragma("unroll") \
    for (int j_ = 0; j_ < 2; j_++) \
    _Pragma("unroll") \
    for (int kk_ = 0; kk_ < 2; kk_++) \
        b[nh][j_][kk_] = *(const bf16x8*)&(cbase)[(kk_ * 8 + wc * 4 + (nh) * 2 + j_) * 512 + lane * 8]; \
} while (0)

#define MM(mh, nh) do { \
    _Pragma("unroll") \
    for (int i_ = 0; i_ < 2; i_++) \
    _Pragma("unroll") \
    for (int j_ = 0; j_ < 2; j_++) \
    _Pragma("unroll") \
    for (int kk_ = 0; kk_ < 2; kk_++) \
        acc[(mh) * 2 + i_][(nh) * 2 + j_] = __builtin_amdgcn_mfma_f32_16x16x32_bf16( \
            a[i_][kk_], b[nh][j_][kk_], acc[(mh) * 2 + i_][(nh) * 2 + j_], 0, 0, 0); \
} while (0)

#define KLOOP do { \
    { \
        unsigned short* a0 = S;                  unsigned short* b0 = S + 16384; \
        unsigned short* a1 = S + 24576;          unsigned short* b1 = S + 24576 + 16384; \
        ST_A(a0, 0, 0); ST_A(a0, 0, 1); ST_B(b0, 0); \
        ST_A(a1, 1, 0); ST_A(a1, 1, 1); ST_B(b1, 1); \
    } \
    VM(6); \
    BAR; \
    unsigned cur = 0; \
    for (int tt = 0; tt < 12; ++tt) { \
        unsigned short* cA = S + cur * 24576; \
        unsigned short* cB = cA + 16384; \
        unsigned sg = cur + 2; if (sg >= 3) sg -= 3; \
        unsigned short* sA = S + sg * 24576; \
        unsigned short* sB = sA + 16384; \
        const bool st = (tt <= 9); \
        RD_A(cA, 0); RD_B(cB, 0); if (st) ST_A(sA, tt + 2, 0); \
        BAR; MM(0, 0); BAR; \
        RD_B(cB, 1); if (st) ST_A(sA, tt + 2, 1); \
        BAR; MM(0, 1); BAR; \
        RD_A(cA, 1); if (st) ST_B(sB, tt + 2); \
        BAR; MM(1, 0); BAR; \
        MM(1, 1); \
        if (tt < 10) { VM(6); } \
        else if (tt == 10) { VM(0); } \
        BAR; \
        cur = cur + 1; if (cur == 3) cur = 0; \
    } \
} while (0)

// ---------------------------------------------------------------------------
// Fused Q + KV GEMM, 1D grid of 384 + 768 = 1152 blocks.
// blocks 0..383: Qt = ctxB * WqT^T (transposed bf16 out).
// blocks 384..1151: Kt/Vb = depB * WkvT^T.
// ---------------------------------------------------------------------------
__global__ __launch_bounds__(512, 2) void gemm_qkv(
    const unsigned short* __restrict__ ctxB, const unsigned short* __restrict__ WqT,
    const unsigned short* __restrict__ depB, const unsigned short* __restrict__ WkvT,
    unsigned short* __restrict__ Qt, unsigned short* __restrict__ Kt,
    unsigned short* __restrict__ Vb)
{
    __shared__ unsigned short S[3 * 24576];      // 3 x (A 32KB + B 16KB)

    int bid = blockIdx.x;
    const bool isQ = (bid < 384);
    const unsigned short* A; const unsigned short* Bt; int lin;
    if (isQ) { A = ctxB; Bt = WqT;  lin = bid; }
    else     { A = depB; Bt = WkvT; lin = bid - 384; }

    const int xcd = lin & 7, li = lin >> 3;
    const int mt = xcd * 8 + (li & 7);            // band = Mt/8 = 8
    const int nt = li >> 3;
    const int bm = mt * 256, bn = nt * 128;

    const int t = threadIdx.x, lane = t & 63, w = t >> 6;
    const int wr = w >> 1, wc = w & 1;            // 4 x 2 wave grid
    const int mf = lane & 15, quad = lane >> 4;

    const unsigned short* gA = A  + (size_t)(bm + (lane & 15)) * KD + (lane >> 4) * 8;
    const unsigned short* gB = Bt + (size_t)(bn + (lane & 15)) * KD + (lane >> 4) * 8;

    f32x4 acc[4][4] = {};
    bf16x8 a[2][2], b[2][2][2];

    KLOOP;

    // epilogue: C/D layout col = lane&15, row = quad*4 + r
    unsigned short* Tr = isQ ? Qt : Kt;           // [bh][96][4096]
    const bool kpart = isQ || (bn < 768);         // uniform per block
    #pragma unroll
    for (int i = 0; i < 4; i++) {
        int row0 = bm + wr * 64 + i * 16 + quad * 4;   // global token index
        int bb = row0 >> 12, n = row0 & 4095;
        #pragma unroll
        for (int j = 0; j < 4; j++) {
            int c = bn + wc * 64 + j * 16 + mf;
            if (kpart) {
                int h = (c * 683) >> 16;          // floor(c/96) for c<768
                int d = c - h * 96;
                size_t o = ((size_t)((bb * 8 + h) * 96 + d)) * 4096 + n;
                ushort4 v4;
                v4.x = f2bf(acc[i][j][0]); v4.y = f2bf(acc[i][j][1]);
                v4.z = f2bf(acc[i][j][2]); v4.w = f2bf(acc[i][j][3]);
                *(ushort4*)&Tr[o] = v4;
            } else {
                int cv = c - 768;
                #pragma unroll
                for (int r = 0; r < 4; r++)
                    Vb[(size_t)(row0 + r) * 768 + cv] = f2bf(acc[i][j][r]);
            }
        }
    }
}

// ---------------------------------------------------------------------------
// Projection GEMM: out = Xb * WprojT^T + bias, fp32 row-major. grid(6,64).
// ---------------------------------------------------------------------------
__global__ __launch_bounds__(512, 2) void gemm_proj(
    const unsigned short* __restrict__ A, const unsigned short* __restrict__ Bt,
    const float* __restrict__ bias, float* __restrict__ C, int N)
{
    __shared__ unsigned short S[3 * 24576];

    const int Nt = gridDim.x, Mt = gridDim.y;
    const int lin = blockIdx.y * Nt + blockIdx.x;
    const int xcd = lin & 7, li = lin >> 3;
    const int band = Mt >> 3;
    const int mt = xcd * band + (li % band);
    const int nt = li / band;
    const int bm = mt * 256, bn = nt * 128;

    const int t = threadIdx.x, lane = t & 63, w = t >> 6;
    const int wr = w >> 1, wc = w & 1;
    const int mf = lane & 15, quad = lane >> 4;

    const unsigned short* gA = A  + (size_t)(bm + (lane & 15)) * KD + (lane >> 4) * 8;
    const unsigned short* gB = Bt + (size_t)(bn + (lane & 15)) * KD + (lane >> 4) * 8;

    f32x4 acc[4][4] = {};
    bf16x8 a[2][2], b[2][2][2];

    KLOOP;

    #pragma unroll
    for (int i = 0; i < 4; i++) {
        int row0 = bm + wr * 64 + i * 16 + quad * 4;
        #pragma unroll
        for (int j = 0; j < 4; j++) {
            int col = bn + wc * 64 + j * 16 + mf;
            float bv = bias[col];
            #pragma unroll
            for (int r = 0; r < 4; r++)
                C[(size_t)(row0 + r) * N + col] = acc[i][j][r] + bv;
        }
    }
}

#undef KLOOP
#undef MM
#undef RD_A
#undef RD_B
#undef ST_A
#undef ST_B
#undef VM
#undef BAR

// ---------------------------------------------------------------------------
// S-gram: Spart[bh][s][96][96] = sum over 512-n window of Qt[d][n]*Kt[e][n].
// ---------------------------------------------------------------------------
__global__ __launch_bounds__(256) void s_gemm(
    const unsigned short* __restrict__ Qt, const unsigned short* __restrict__ Kt,
    float* __restrict__ Spart, float* __restrict__ ssq)
{
    __shared__ unsigned short Qs[2][12 * 512];
    __shared__ unsigned short Ks[2][12 * 512];
    const int s = blockIdx.x, bh = blockIdx.y;
    const int t = threadIdx.x, lane = t & 63, w = t >> 6;
    const int m0 = (w >> 1) * 48, n0w = (w & 1) * 48;
    const int mf = lane & 15, quad = lane >> 4;
    const int srow = lane & 15, skc = (lane >> 4) * 8;
    const int nwin = s * 512;

    const unsigned short* Qg = Qt + (size_t)bh * 96 * 4096;
    const unsigned short* Kg = Kt + (size_t)bh * 96 * 4096;

    f32x4 acc[3][3] = {};
    float sq[3] = {0.f, 0.f, 0.f}, sk[3] = {0.f, 0.f, 0.f};

    #pragma unroll
    for (int c = 0; c < 3; c++) {
        int bi = w * 3 + c, kc = bi / 6, g = bi % 6;
        size_t go = (size_t)(g * 16 + srow) * 4096 + nwin + kc * 32 + skc;
        glds16(Qg + go, &Qs[0][bi * 512]);
        glds16(Kg + go, &Ks[0][bi * 512]);
    }

    for (int it = 0; it < 8; it++) {
        const int cur = it & 1;
        __syncthreads();
        if (it + 1 < 8) {
            const int nxt = cur ^ 1;
            const int nn = nwin + (it + 1) * 64;
            #pragma unroll
            for (int c = 0; c < 3; c++) {
                int bi = w * 3 + c, kc = bi / 6, g = bi % 6;
                size_t go = (size_t)(g * 16 + srow) * 4096 + nn + kc * 32 + skc;
                glds16(Qg + go, &Qs[nxt][bi * 512]);
                glds16(Kg + go, &Ks[nxt][bi * 512]);
            }
        }
        #pragma unroll
        for (int kk = 0; kk < 2; kk++) {
            bf16x8 a[3], b[3];
            #pragma unroll
            for (int i = 0; i < 3; i++)
                a[i] = *(const bf16x8*)&Qs[cur][(kk * 6 + (w >> 1) * 3 + i) * 512 + lane * 8];
            #pragma unroll
            for (int j = 0; j < 3; j++)
                b[j] = *(const bf16x8*)&Ks[cur][(kk * 6 + (w & 1) * 3 + j) * 512 + lane * 8];
            if ((w & 1) == 0) {
                #pragma unroll
                for (int i = 0; i < 3; i++) sq[i] += ssq8(a[i]);
            }
            if ((w >> 1) == 0) {
                #pragma unroll
                for (int j = 0; j < 3; j++) sk[j] += ssq8(b[j]);
            }
            #pragma unroll
            for (int i = 0; i < 3; i++)
                #pragma unroll
                for (int j = 0; j < 3; j++)
                    acc[i][j] = __builtin_amdgcn_mfma_f32_16x16x32_bf16(a[i], b[j], acc[i][j], 0, 0, 0);
        }
    }

    if ((w & 1) == 0) {
        #pragma unroll
        for (int i = 0; i < 3; i++) {
            float v = sq[i];
            v += __shfl_xor(v, 16, 64);
            v += __shfl_xor(v, 32, 64);
            if (lane < 16) atomicAdd(&ssq[bh * 96 + m0 + i * 16 + lane], v);
        }
    }
    if ((w >> 1) == 0) {
        #pragma unroll
        for (int j = 0; j < 3; j++) {
            float v = sk[j];
            v += __shfl_xor(v, 16, 64);
            v += __shfl_xor(v, 32, 64);
            if (lane < 16) atomicAdd(&ssq[3072 + bh * 96 + n0w + j * 16 + lane], v);
        }
    }

    float* outp = Spart + (size_t)(bh * 8 + s) * 9216;
    #pragma unroll
    for (int i = 0; i < 3; i++)
        #pragma unroll
        for (int j = 0; j < 3; j++) {
            int e  = n0w + j * 16 + mf;
            int d0 = m0 + i * 16 + quad * 4;
            #pragma unroll
            for (int r = 0; r < 4; r++)
                outp[(d0 + r) * 96 + e] = acc[i][j][r];
        }
}

// ---------------------------------------------------------------------------
// Softmax, wave-per-row: grid(24, 32bh) x 256 thr.
// ---------------------------------------------------------------------------
__global__ __launch_bounds__(256) void softmax_k(
    const float* __restrict__ Spart, const float* __restrict__ ssq,
    unsigned short* __restrict__ P)
{
    const int bh = blockIdx.y;
    const int d  = blockIdx.x * 4 + (threadIdx.x >> 6);
    const int lane = threadIdx.x & 63;

    const float sr = SCALE_ / fmaxf(sqrtf(ssq[bh * 96 + d]), 1e-12f);

    const float* Sp = Spart + (size_t)bh * 8 * 9216 + d * 96;
    float sa = 0.f, sb = 0.f;
    #pragma unroll
    for (int ch = 0; ch < 8; ch++) {
        sa += Sp[ch * 9216 + lane];
        if (lane < 32) sb += Sp[ch * 9216 + 64 + lane];
    }
    float ka = 1.0f / fmaxf(sqrtf(ssq[3072 + bh * 96 + lane]), 1e-12f);
    float va = sa * sr * ka;
    float vb = -1e30f;
    if (lane < 32) {
        float kb = 1.0f / fmaxf(sqrtf(ssq[3072 + bh * 96 + 64 + lane]), 1e-12f);
        vb = sb * sr * kb;
    }

    float m = fmaxf(va, vb);
    #pragma unroll
    for (int off = 32; off >= 1; off >>= 1)
        m = fmaxf(m, __shfl_xor(m, off, 64));

    float ea = __expf(va - m);
    float eb = (lane < 32) ? __expf(vb - m) : 0.f;
    float ssum = ea + eb;
    #pragma unroll
    for (int off = 32; off >= 1; off >>= 1)
        ssum += __shfl_xor(ssum, off, 64);

    float inv = 1.0f / ssum;
    unsigned short* Pr = P + (size_t)bh * 9216 + d * 96;
    Pr[lane] = f2bf(ea * inv);
    if (lane < 32) Pr[64 + lane] = f2bf(eb * inv);
}

// ---------------------------------------------------------------------------
// x[n][d] = sum_e V[n][e] * P[d][e] per (b,h). V from compact Vb[m][768].
// ---------------------------------------------------------------------------
__global__ __launch_bounds__(256) void pv_gemm(
    const unsigned short* __restrict__ Vb, const unsigned short* __restrict__ P,
    unsigned short* __restrict__ X)
{
    __shared__ unsigned short Ps[96][104];
    int ntile = blockIdx.x, bh = blockIdx.y;
    int b = bh >> 3, h = bh & 7;
    int t = threadIdx.x, lane = t & 63, w = t >> 6;

    const unsigned short* Pg = P + (size_t)bh * 9216;
    #pragma unroll
    for (int i = 0; i < 9; i++) {
        int idx4 = t + 256 * i;
        int row = idx4 / 24, c4 = (idx4 - row * 24) * 4;
        *(ushort4*)&Ps[row][c4] = *(const ushort4*)&Pg[row * 96 + c4];
    }
    __syncthreads();

    const unsigned short* Vbase = Vb + (size_t)b * 4096 * 768 + h * 96;
    int mf = lane & 15, k8 = (lane >> 4) * 8;
    f32x4 acc[2][6] = {};
    #pragma unroll
    for (int k = 0; k < 3; k++) {
        bf16x8 a[2], bb[6];
        #pragma unroll
        for (int i = 0; i < 2; i++) {
            int row = ntile * 128 + w * 32 + i * 16 + mf;
            a[i] = *(const bf16x8*)&Vbase[(size_t)row * 768 + k * 32 + k8];
        }
        #pragma unroll
        for (int j = 0; j < 6; j++)
            bb[j] = *(const bf16x8*)&Ps[j * 16 + mf][k * 32 + k8];
        #pragma unroll
        for (int i = 0; i < 2; i++)
            #pragma unroll
            for (int j = 0; j < 6; j++)
                acc[i][j] = __builtin_amdgcn_mfma_f32_16x16x32_bf16(a[i], bb[j], acc[i][j], 0, 0, 0);
    }
    #pragma unroll
    for (int i = 0; i < 2; i++)
        #pragma unroll
        for (int j = 0; j < 6; j++)
            #pragma unroll
            for (int r = 0; r < 4; r++) {
                int n_tok = ntile * 128 + w * 32 + i * 16 + (lane >> 4) * 4 + r;
                int c = h * 96 + j * 16 + mf;
                X[((size_t)b * 4096 + n_tok) * 768 + c] = f2bf(acc[i][j][r]);
            }
}

// ---------------------------------------------------------------------------
extern "C" void kernel_launch(void* const* d_in, const int* in_sizes, int n_in,
                              void* d_out, int out_size, void* d_ws, size_t ws_size,
                              hipStream_t stream)
{
    (void)in_sizes; (void)n_in; (void)out_size; (void)ws_size;
    const float* ctx   = (const float*)d_in[0];
    const float* dep   = (const float*)d_in[1];
    const float* Wq    = (const float*)d_in[2];
    const float* Wkv   = (const float*)d_in[3];
    const float* Wproj = (const float*)d_in[4];
    const float* bproj = (const float*)d_in[5];
    float* out = (float*)d_out;

    char* p = (char*)d_ws;
    auto carve = [&](size_t bytes) {
        char* r = p;
        p += (bytes + 255) & ~(size_t)255;
        return r;
    };
    unsigned short* WqT    = (unsigned short*)carve((size_t)768 * 768 * 2);
    unsigned short* WkvT   = (unsigned short*)carve((size_t)1536 * 768 * 2);
    unsigned short* WprojT = (unsigned short*)carve((size_t)768 * 768 * 2);
    unsigned short* Qt     = (unsigned short*)carve((size_t)32 * 96 * 4096 * 2);
    unsigned short* Kt     = (unsigned short*)carve((size_t)32 * 96 * 4096 * 2);
    unsigned short* Vb     = (unsigned short*)carve((size_t)16384 * 768 * 2);
    unsigned short* Xb     = (unsigned short*)carve((size_t)16384 * 768 * 2);
    float*          ssq    = (float*)carve((size_t)2 * 3072 * 4);
    float*          Spart  = (float*)carve((size_t)32 * 8 * 9216 * 4);
    unsigned short* Pb     = (unsigned short*)carve((size_t)32 * 9216 * 2);
    unsigned short* depB   = (unsigned short*)carve((size_t)16384 * 768 * 2);
    // ctx-bf16 aliases Xb: Q-gemm consumes it before pv_gemm writes Xb.
    unsigned short* ctxB   = Xb;

    hipMemsetAsync(ssq, 0, 2 * 3072 * 4, stream);

    prep_k<<<14592, 256, 0, stream>>>(ctx, ctxB, dep, depB,
                                      Wq, WqT, Wkv, WkvT, Wproj, WprojT);

    gemm_qkv<<<1152, 512, 0, stream>>>(ctxB, WqT, depB, WkvT, Qt, Kt, Vb);

    s_gemm<<<dim3(8, 32), 256, 0, stream>>>(Qt, Kt, Spart, ssq);
    softmax_k<<<dim3(24, 32), 256, 0, stream>>>(Spart, ssq, Pb);
    pv_gemm<<<dim3(32, 32), 256, 0, stream>>>(Vb, Pb, Xb);
    gemm_proj<<<dim3(6, 64), 512, 0, stream>>>(Xb, WprojT, bproj, out, 768);
}